// Round 3
// baseline (41421.292 us; speedup 1.0000x reference)
//
#include <hip/hip_runtime.h>
#include <hip/hip_bf16.h>
#include <hip/hip_cooperative_groups.h>

namespace cg = cooperative_groups;

// CharRNN: embed -> 4x (LayerNorm-LSTM over T=128) -> projection to vocab.
// Round 2: persistent cooperative kernel per layer for the recurrence
// (128 timesteps, 2 grid syncs each) replacing 1024 tiny dispatches.
// Numerics identical to round 1 (3-term split-bf16 MFMA everywhere on the
// recurrent path; plain bf16 projection).

typedef __bf16 bf16x8 __attribute__((ext_vector_type(8)));
typedef __bf16 bf16x4 __attribute__((ext_vector_type(4)));
typedef float  f32x4  __attribute__((ext_vector_type(4)));

#define VOCAB 32000
#define BATCH 32
#define SEQ   128
#define RNN   1024
#define NLAY  4
#define GBLK  128   // persistent grid: blocks (each owns 32 cols of Wh)

__device__ __forceinline__ float sigm(float x) { return 1.f / (1.f + __expf(-x)); }

// ---------------------------------------------------------------------------
// W [L][2048][4096] f32 -> Wt [L][2 planes (hi,lo)][4096][2048] bf16,
// transposed to [n][k]. k 0..1023 = x-part (Wx), k 1024..2047 = h-part (Wh).
__global__ __launch_bounds__(256) void k_cvt_w(const float* __restrict__ W,
                                               __bf16* __restrict__ Wt) {
    __shared__ float lds[64][65];
    const int tid = threadIdx.x, tx = tid & 15, ty = tid >> 4;
    const int n0 = blockIdx.x * 64, k0 = blockIdx.y * 64;
    const size_t l = blockIdx.z;
    const float* src = W + (l * 2048 + (size_t)k0) * 4096 + n0;
#pragma unroll
    for (int rr = 0; rr < 4; ++rr) {
        int kr = rr * 16 + ty;
        f32x4 v = *(const f32x4*)(src + (size_t)kr * 4096 + tx * 4);
        lds[kr][tx*4+0] = v[0]; lds[kr][tx*4+1] = v[1];
        lds[kr][tx*4+2] = v[2]; lds[kr][tx*4+3] = v[3];
    }
    __syncthreads();
    __bf16* dhi = Wt + ((l * 2 + 0) * 4096 + (size_t)n0) * 2048 + k0;
    __bf16* dlo = Wt + ((l * 2 + 1) * 4096 + (size_t)n0) * 2048 + k0;
#pragma unroll
    for (int rr = 0; rr < 4; ++rr) {
        int nr = rr * 16 + ty;
        bf16x4 ohi, olo;
#pragma unroll
        for (int j = 0; j < 4; ++j) {
            float x = lds[tx*4+j][nr];
            __bf16 h = (__bf16)x;
            ohi[j] = h;
            olo[j] = (__bf16)(x - (float)h);
        }
        *(bf16x4*)(dhi + (size_t)nr * 2048 + tx * 4) = ohi;
        *(bf16x4*)(dlo + (size_t)nr * 2048 + tx * 4) = olo;
    }
}

// plain f32 -> bf16 (hi only), 8 elems/thread, exact grid
__global__ __launch_bounds__(256) void k_cvt(const float* __restrict__ in,
                                             __bf16* __restrict__ out) {
    size_t i = ((size_t)blockIdx.x * 256 + threadIdx.x) * 8;
    f32x4 v0 = *(const f32x4*)(in + i);
    f32x4 v1 = *(const f32x4*)(in + i + 4);
    bf16x8 o;
    o[0]=(__bf16)v0[0]; o[1]=(__bf16)v0[1]; o[2]=(__bf16)v0[2]; o[3]=(__bf16)v0[3];
    o[4]=(__bf16)v1[0]; o[5]=(__bf16)v1[1]; o[6]=(__bf16)v1[2]; o[7]=(__bf16)v1[3];
    *(bf16x8*)(out + i) = o;
}

// embedding gather -> time-major [t*32+b][1024] hi/lo bf16
__global__ __launch_bounds__(256) void k_embed(const int* __restrict__ idx,
                                               const float* __restrict__ emb,
                                               __bf16* __restrict__ xhi,
                                               __bf16* __restrict__ xlo) {
    const int row = blockIdx.x;            // t*32 + b
    const int t = row >> 5, b = row & 31;
    const int id = idx[b * SEQ + t];
    const int tid = threadIdx.x;
    f32x4 v = *(const f32x4*)(emb + (size_t)id * RNN + tid * 4);
    bf16x4 hi, lo;
#pragma unroll
    for (int j = 0; j < 4; ++j) {
        __bf16 h = (__bf16)v[j];
        hi[j] = h; lo[j] = (__bf16)(v[j] - (float)h);
    }
    *(bf16x4*)(xhi + (size_t)row * RNN + tid * 4) = hi;
    *(bf16x4*)(xlo + (size_t)row * RNN + tid * 4) = lo;
}

// ---------------------------------------------------------------------------
// zx[4096][4096] = X @ Wx + bias, 3-term split bf16 MFMA (fp32-grade).
// Block = 64(M) x 64(N); wave = 4 m-tiles x 16 n.
__global__ __launch_bounds__(256) void k_xgemm(const __bf16* __restrict__ xhi,
                                               const __bf16* __restrict__ xlo,
                                               const __bf16* __restrict__ Wt, // layer base
                                               const float* __restrict__ bias,
                                               float* __restrict__ zx) {
    const int tid = threadIdx.x;
    const int lane = tid & 63, w = tid >> 6;
    const int g = lane >> 4, q = lane & 15;
    const int n = blockIdx.x * 64 + w * 16 + q;
    const int m0 = blockIdx.y * 64;
    const int ko = g * 8;
    const __bf16* bh = Wt + (size_t)n * 2048;              // hi plane, k in [0,1024)
    const __bf16* bl = Wt + ((size_t)4096 + n) * 2048;     // lo plane
    f32x4 acc[4] = {{0,0,0,0},{0,0,0,0},{0,0,0,0},{0,0,0,0}};
    const __bf16 *ah[4], *al[4];
#pragma unroll
    for (int mt = 0; mt < 4; ++mt) {
        int m = m0 + mt * 16 + q;
        ah[mt] = xhi + (size_t)m * RNN;
        al[mt] = xlo + (size_t)m * RNN;
    }
#pragma unroll 2
    for (int k0 = 0; k0 < RNN; k0 += 32) {
        bf16x8 bhf = *(const bf16x8*)(bh + k0 + ko);
        bf16x8 blf = *(const bf16x8*)(bl + k0 + ko);
#pragma unroll
        for (int mt = 0; mt < 4; ++mt) {
            bf16x8 ahf = *(const bf16x8*)(ah[mt] + k0 + ko);
            bf16x8 alf = *(const bf16x8*)(al[mt] + k0 + ko);
            acc[mt] = __builtin_amdgcn_mfma_f32_16x16x32_bf16(ahf, bhf, acc[mt], 0, 0, 0);
            acc[mt] = __builtin_amdgcn_mfma_f32_16x16x32_bf16(alf, bhf, acc[mt], 0, 0, 0);
            acc[mt] = __builtin_amdgcn_mfma_f32_16x16x32_bf16(ahf, blf, acc[mt], 0, 0, 0);
        }
    }
    const float bv = bias[n];
#pragma unroll
    for (int mt = 0; mt < 4; ++mt)
#pragma unroll
        for (int r = 0; r < 4; ++r) {
            int m = m0 + mt * 16 + g * 4 + r;
            zx[(size_t)m * 4096 + n] = acc[mt][r] + bv;
        }
}

// ---------------------------------------------------------------------------
// Persistent per-layer recurrence. GBLK blocks x 256 threads, cooperative.
// Per step: phase A  z[32,4096] = zx[t] + h@Wh (3-term split MFMA), each
// block owns 32 n-cols (Wh slice 128 KB -> L2-resident); grid sync; phase B
// gates (32 blocks, one per batch row); grid sync.
__global__ __launch_bounds__(256, 1) void k_lstm_seq(
        const __bf16* __restrict__ Wt,   // layer base (hi plane; lo at +4096*2048)
        const float* __restrict__ zx,    // [SEQ*BATCH][4096]
        float* __restrict__ z,           // [BATCH][4096] scratch
        __bf16* __restrict__ hhi, __bf16* __restrict__ hlo,
        float* __restrict__ c,
        __bf16* __restrict__ xhi, __bf16* __restrict__ xlo,  // layer output rows
        const float* __restrict__ g5, const float* __restrict__ b5) {
    cg::grid_group grid = cg::this_grid();
    const int bk = blockIdx.x, tid = threadIdx.x;
    const int lane = tid & 63, w = tid >> 6, wv = w;
    const int q = lane & 15, g = lane >> 4;
    const int ko = g * 8;

    // phase A geometry: wave w -> m-tile (w&1), col-tile (w>>1)
    const int mrow = (w & 1) * 16 + q;            // A-frag row (batch)
    const int ncol = bk * 32 + (w >> 1) * 16 + q; // B-frag col (z col)
    const int zrow0 = (w & 1) * 16 + g * 4;       // D rows base
    const __bf16* bh = Wt + (size_t)ncol * 2048 + RNN;          // Wh hi
    const __bf16* bl = Wt + ((size_t)4096 + ncol) * 2048 + RNN; // Wh lo
    const __bf16* ahp = hhi + (size_t)mrow * RNN;
    const __bf16* alp = hlo + (size_t)mrow * RNN;

    __shared__ float red[4][8];

    // phase B constants (row b = bk), hoisted out of the t-loop
    const bool gates_blk = (bk < BATCH);
    f32x4 gi, bi, gj, bj, gf, bfv, go, bo, g4, b4;
    if (gates_blk) {
        gi = *(const f32x4*)(g5 + 0*RNN + tid*4); bi = *(const f32x4*)(b5 + 0*RNN + tid*4);
        gj = *(const f32x4*)(g5 + 1*RNN + tid*4); bj = *(const f32x4*)(b5 + 1*RNN + tid*4);
        gf = *(const f32x4*)(g5 + 2*RNN + tid*4); bfv= *(const f32x4*)(b5 + 2*RNN + tid*4);
        go = *(const f32x4*)(g5 + 3*RNN + tid*4); bo = *(const f32x4*)(b5 + 3*RNN + tid*4);
        g4 = *(const f32x4*)(g5 + 4*RNN + tid*4); b4 = *(const f32x4*)(b5 + 4*RNN + tid*4);
    }
    const float inv = 1.f / (float)RNN;

    for (int t = 0; t < SEQ; ++t) {
        // ---------------- phase A ----------------
        f32x4 acc = {0.f, 0.f, 0.f, 0.f};
        if (t > 0) {
#pragma unroll 4
            for (int k0 = 0; k0 < RNN; k0 += 32) {
                bf16x8 bhf = *(const bf16x8*)(bh + k0 + ko);
                bf16x8 blf = *(const bf16x8*)(bl + k0 + ko);
                bf16x8 ahf = *(const bf16x8*)(ahp + k0 + ko);
                bf16x8 alf = *(const bf16x8*)(alp + k0 + ko);
                acc = __builtin_amdgcn_mfma_f32_16x16x32_bf16(ahf, bhf, acc, 0, 0, 0);
                acc = __builtin_amdgcn_mfma_f32_16x16x32_bf16(alf, bhf, acc, 0, 0, 0);
                acc = __builtin_amdgcn_mfma_f32_16x16x32_bf16(ahf, blf, acc, 0, 0, 0);
            }
        }
        {
            const float* zxr = zx + ((size_t)t * BATCH + zrow0) * 4096 + ncol;
#pragma unroll
            for (int r = 0; r < 4; ++r)
                z[(size_t)(zrow0 + r) * 4096 + ncol] = acc[r] + zxr[(size_t)r * 4096];
        }
        __threadfence();
        grid.sync();   // z complete

        // ---------------- phase B ----------------
        if (gates_blk) {
            const int b = bk;
            const f32x4* zr = (const f32x4*)(z + (size_t)b * 4096);
            f32x4 zi = zr[tid], zjv = zr[256 + tid], zfv = zr[512 + tid], zov = zr[768 + tid];
            float s[8];
            s[0] = zi[0]+zi[1]+zi[2]+zi[3];
            s[1] = zi[0]*zi[0]+zi[1]*zi[1]+zi[2]*zi[2]+zi[3]*zi[3];
            s[2] = zjv[0]+zjv[1]+zjv[2]+zjv[3];
            s[3] = zjv[0]*zjv[0]+zjv[1]*zjv[1]+zjv[2]*zjv[2]+zjv[3]*zjv[3];
            s[4] = zfv[0]+zfv[1]+zfv[2]+zfv[3];
            s[5] = zfv[0]*zfv[0]+zfv[1]*zfv[1]+zfv[2]*zfv[2]+zfv[3]*zfv[3];
            s[6] = zov[0]+zov[1]+zov[2]+zov[3];
            s[7] = zov[0]*zov[0]+zov[1]*zov[1]+zov[2]*zov[2]+zov[3]*zov[3];
#pragma unroll
            for (int o = 32; o; o >>= 1)
#pragma unroll
                for (int i = 0; i < 8; ++i) s[i] += __shfl_xor(s[i], o);
            if (lane == 0) {
#pragma unroll
                for (int i = 0; i < 8; ++i) red[wv][i] = s[i];
            }
            __syncthreads();
            float tot[8];
#pragma unroll
            for (int i = 0; i < 8; ++i) tot[i] = red[0][i]+red[1][i]+red[2][i]+red[3][i];

            float mi = tot[0]*inv, ri = rsqrtf(tot[1]*inv - mi*mi + 1e-5f);
            float mj = tot[2]*inv, rj = rsqrtf(tot[3]*inv - mj*mj + 1e-5f);
            float mf = tot[4]*inv, rf = rsqrtf(tot[5]*inv - mf*mf + 1e-5f);
            float mo = tot[6]*inv, ro = rsqrtf(tot[7]*inv - mo*mo + 1e-5f);

            f32x4 cold = {0.f, 0.f, 0.f, 0.f};
            if (t > 0) cold = *(const f32x4*)(c + (size_t)b * RNN + tid * 4);

            f32x4 cnew, onrm;
            float cs = 0.f, cq = 0.f;
#pragma unroll
            for (int j = 0; j < 4; ++j) {
                float iv = (zi[j]-mi)*ri*gi[j] + bi[j];
                float jv = (zjv[j]-mj)*rj*gj[j] + bj[j];
                float fv = (zfv[j]-mf)*rf*gf[j] + bfv[j];
                float ov = (zov[j]-mo)*ro*go[j] + bo[j];
                float cc = cold[j] * sigm(fv + 1.0f) + sigm(iv) * tanhf(jv);
                cnew[j] = cc; onrm[j] = ov;
                cs += cc; cq += cc*cc;
            }
            *(f32x4*)(c + (size_t)b * RNN + tid * 4) = cnew;

            __syncthreads();   // protect red[] reuse
            float s2a = cs, s2b = cq;
#pragma unroll
            for (int o = 32; o; o >>= 1) { s2a += __shfl_xor(s2a, o); s2b += __shfl_xor(s2b, o); }
            if (lane == 0) { red[wv][0] = s2a; red[wv][1] = s2b; }
            __syncthreads();
            float mc = (red[0][0]+red[1][0]+red[2][0]+red[3][0]) * inv;
            float vc = (red[0][1]+red[1][1]+red[2][1]+red[3][1]) * inv - mc*mc;
            float rc = rsqrtf(vc + 1e-5f);

            bf16x4 hh, hl;
#pragma unroll
            for (int j = 0; j < 4; ++j) {
                float cn = (cnew[j]-mc)*rc*g4[j] + b4[j];
                float h = tanhf(cn) * sigm(onrm[j]);
                __bf16 a = (__bf16)h;
                hh[j] = a; hl[j] = (__bf16)(h - (float)a);
            }
            *(bf16x4*)(hhi + (size_t)b * RNN + tid * 4) = hh;
            *(bf16x4*)(hlo + (size_t)b * RNN + tid * 4) = hl;
            *(bf16x4*)(xhi + ((size_t)t * BATCH + b) * RNN + tid * 4) = hh;
            *(bf16x4*)(xlo + ((size_t)t * BATCH + b) * RNN + tid * 4) = hl;
        }
        __threadfence();
        grid.sync();   // h complete
    }
}

// ---------------------------------------------------------------------------
// logits[m][v] = sum_k h[m][k]*smw[v][k] + smb[v], m = b*128+t; plain bf16.
// Source row in time-major buffer = (m&127)*32 + (m>>7).
__global__ __launch_bounds__(256) void k_proj(const __bf16* __restrict__ xs,
                                              const __bf16* __restrict__ wv,
                                              const float* __restrict__ sb,
                                              float* __restrict__ out) {
    const int tid = threadIdx.x;
    const int lane = tid & 63, w = tid >> 6;
    const int g = lane >> 4, q = lane & 15;
    const int n = blockIdx.x * 64 + w * 16 + q;
    const int m0 = blockIdx.y * 64;
    const int ko = g * 8;
    f32x4 acc[4] = {{0,0,0,0},{0,0,0,0},{0,0,0,0},{0,0,0,0}};
    const __bf16* arow[4];
#pragma unroll
    for (int mt = 0; mt < 4; ++mt) {
        int m = m0 + mt * 16 + q;
        arow[mt] = xs + (size_t)((m & 127) * 32 + (m >> 7)) * RNN;
    }
    const __bf16* brow = wv + (size_t)n * RNN;
#pragma unroll 2
    for (int k0 = 0; k0 < RNN; k0 += 32) {
        bf16x8 bfr = *(const bf16x8*)(brow + k0 + ko);
#pragma unroll
        for (int mt = 0; mt < 4; ++mt) {
            bf16x8 afr = *(const bf16x8*)(arow[mt] + k0 + ko);
            acc[mt] = __builtin_amdgcn_mfma_f32_16x16x32_bf16(afr, bfr, acc[mt], 0, 0, 0);
        }
    }
    const float bv = sb[n];
#pragma unroll
    for (int mt = 0; mt < 4; ++mt)
#pragma unroll
        for (int r = 0; r < 4; ++r) {
            int m = m0 + mt * 16 + g * 4 + r;
            out[(size_t)m * VOCAB + n] = acc[mt][r] + bv;
        }
}

// ---------------------------------------------------------------------------
extern "C" void kernel_launch(void* const* d_in, const int* in_sizes, int n_in,
                              void* d_out, int out_size, void* d_ws, size_t ws_size,
                              hipStream_t stream) {
    const int*   input = (const int*)  d_in[0];
    const float* emb   = (const float*)d_in[1];
    const float* W     = (const float*)d_in[2];
    const float* bias  = (const float*)d_in[3];
    const float* ln_g  = (const float*)d_in[4];
    const float* ln_b  = (const float*)d_in[5];
    const float* smw   = (const float*)d_in[6];
    const float* smb   = (const float*)d_in[7];
    float* out = (float*)d_out;

    char* p = (char*)d_ws;
    auto alloc = [&](size_t bytes) { char* r = p; p += (bytes + 255) & ~(size_t)255; return r; };
    __bf16* Wt   = (__bf16*)alloc((size_t)NLAY * 2 * 4096 * 2048 * 2); // 134.2 MB (hi+lo)
    __bf16* smwb = (__bf16*)alloc((size_t)VOCAB * RNN * 2);            // 65.5 MB
    __bf16* xhi  = (__bf16*)alloc((size_t)SEQ * BATCH * RNN * 2);      // 8.4 MB
    __bf16* xlo  = (__bf16*)alloc((size_t)SEQ * BATCH * RNN * 2);      // 8.4 MB
    float*  zx   = (float*) alloc((size_t)SEQ * BATCH * 4096 * 4);     // 67.1 MB
    float*  z    = (float*) alloc((size_t)BATCH * 4096 * 4);           // 512 KB
    __bf16* hhi  = (__bf16*)alloc((size_t)BATCH * RNN * 2);            // 64 KB
    __bf16* hlo  = (__bf16*)alloc((size_t)BATCH * RNN * 2);            // 64 KB
    float*  c    = (float*) alloc((size_t)BATCH * RNN * 4);            // 128 KB

    k_cvt_w<<<dim3(64, 32, NLAY), 256, 0, stream>>>(W, Wt);
    k_cvt<<<(VOCAB * RNN) / (8 * 256), 256, 0, stream>>>(smw, smwb);
    k_embed<<<SEQ * BATCH, 256, 0, stream>>>(input, emb, xhi, xlo);

    for (int l = 0; l < NLAY; ++l) {
        const __bf16* Wl  = Wt + (size_t)l * 2 * 4096 * 2048;
        const float*  bl  = bias + (size_t)l * 4096;
        const float*  gl  = ln_g + (size_t)l * 5 * RNN;
        const float*  bbl = ln_b + (size_t)l * 5 * RNN;
        // x-part for all timesteps (parallel GEMM, bias folded)
        k_xgemm<<<dim3(64, 64), 256, 0, stream>>>(xhi, xlo, Wl, bl, zx);
        // recurrence: one cooperative launch per layer
        {
            const __bf16* Wl_  = Wl;
            const float*  zx_  = zx;
            float*        z_   = z;
            __bf16*       hhi_ = hhi; __bf16* hlo_ = hlo;
            float*        c_   = c;
            __bf16*       xhi_ = xhi; __bf16* xlo_ = xlo;
            const float*  gl_  = gl;  const float* bbl_ = bbl;
            void* args[] = {(void*)&Wl_, (void*)&zx_, (void*)&z_,
                            (void*)&hhi_, (void*)&hlo_, (void*)&c_,
                            (void*)&xhi_, (void*)&xlo_, (void*)&gl_, (void*)&bbl_};
            hipLaunchCooperativeKernel((const void*)k_lstm_seq,
                                       dim3(GBLK), dim3(256), args, 0, stream);
        }
    }
    // after l=3, final layer output (bf16 hi) lives in xhi (time-major)
    k_proj<<<dim3(VOCAB / 64, 4096 / 64), 256, 0, stream>>>(xhi, smwb, smb, out);
}